// Round 2
// baseline (139.094 us; speedup 1.0000x reference)
//
#include <hip/hip_runtime.h>

#define BB 64
#define LL 2048
#define KK 30
#define VV 33
#define TTMAX 500
#define CHUNK 256
#define NCH (LL / CHUNK)   // 8 chunks per batch

__global__ __launch_bounds__(256) void lvb_main(
    const float* __restrict__ src, const float* __restrict__ q,
    const float* __restrict__ pred, const int* __restrict__ tgt,
    const float* __restrict__ mask, const int* __restrict__ tsteps,
    const float* __restrict__ Qm, const float* __restrict__ Qbar,
    float* __restrict__ ws)
{
    __shared__ float s_tile[CHUNK * VV];   // pred rows (stride 33) or q rows (stride 31)
    __shared__ float s_qbm1[KK * 31];      // Q_bar[t-1], row-major padded
    __shared__ float s_qtT[KK * 31];       // Q[t] transposed, padded: s_qtT[j][k] = Qt[k][j]
    __shared__ int   s_xt[CHUNK];
    __shared__ float s_red[8];

    const int tid = threadIdx.x;
    const int ch  = blockIdx.x;
    const int b   = blockIdx.y;
    const int l0  = ch * CHUNK;
    const int idx = b * LL + l0 + tid;
    const int t   = tsteps[b];

    float val = 0.f, cnt = 0.f;
    const bool m_on = (mask[idx] > 0.5f);

    if (t == 1) {
        // ---- cross-entropy branch: needs predictions + tgt only ----
        const float* g = pred + (size_t)(b * LL + l0) * VV;
        for (int i = tid; i < CHUNK * VV; i += 256) s_tile[i] = g[i];
        __syncthreads();
        const float* row = &s_tile[tid * VV];
        float mx = row[0];
        #pragma unroll
        for (int j = 1; j < KK; ++j) mx = fmaxf(mx, row[j]);
        float se = 0.f;
        #pragma unroll
        for (int j = 0; j < KK; ++j) se += __expf(row[j] - mx);
        const int tg = tgt[idx];
        const float ce = -(row[tg] - mx - __logf(se));
        if (m_on) { val = ce; cnt = 1.f; }
    } else if (t == TTMAX) {
        // ---- KL-prior branch: needs q only ----
        const float* g = q + (size_t)(b * LL + l0) * KK;
        for (int i = tid; i < CHUNK * KK; i += 256) {
            int r = i / KK, c = i - r * KK;
            s_tile[r * 31 + c] = g[i];
        }
        __syncthreads();
        const float* row = &s_tile[tid * 31];
        float S = 0.f, t1 = 0.f;
        #pragma unroll
        for (int j = 0; j < KK; ++j) { float v = row[j]; S += v; t1 += v * __logf(v); }
        const float klp = t1 / S - __logf(S) + __logf((float)KK);
        if (m_on) { val = klp; cnt = 1.f; }
    } else {
        // ---- middle KL branch ----
        const float* g = pred + (size_t)(b * LL + l0) * VV;
        for (int i = tid; i < CHUNK * VV; i += 256) s_tile[i] = g[i];

        const int tm1 = (t - 1 > 0) ? t - 1 : 0;
        const float* gq = Qbar + (size_t)tm1 * KK * KK;
        const float* gt = Qm + (size_t)t * KK * KK;
        for (int i = tid; i < KK * KK; i += 256) {
            int r = i / KK, c = i - r * KK;
            s_qbm1[r * 31 + c] = gq[i];
            s_qtT[c * 31 + r]  = gt[i];
        }
        // recover xt from src_onehot during the coalesced scan
        const float* gs = src + (size_t)(b * LL + l0) * KK;
        for (int i = tid; i < CHUNK * KK; i += 256) {
            if (gs[i] > 0.5f) { int r = i / KK; s_xt[r] = i - r * KK; }
        }
        __syncthreads();

        const float* row = &s_tile[tid * VV];
        float mx = row[0];
        #pragma unroll
        for (int j = 1; j < KK; ++j) mx = fmaxf(mx, row[j]);
        float e[KK]; float se = 0.f;
        #pragma unroll
        for (int j = 0; j < KK; ++j) { e[j] = __expf(row[j] - mx); se += e[j]; }
        const float inv2 = 1.f / (se * se);

        float s[KK];
        #pragma unroll
        for (int k = 0; k < KK; ++k) s[k] = 0.f;
        #pragma unroll
        for (int j = 0; j < KK; ++j) {
            const float pj2 = e[j] * e[j] * inv2;
            #pragma unroll
            for (int k = 0; k < KK; ++k) s[k] += pj2 * s_qbm1[j * 31 + k];
        }

        const int tg = tgt[idx];
        const int xt = s_xt[tid];
        const float* Arow = &s_qtT[xt * 31];
        const float* Brow = &s_qbm1[tg * 31];

        float Snum = 0.f, Spt = 0.f;
        #pragma unroll
        for (int k = 0; k < KK; ++k) {
            const float A = Arow[k], Bv = Brow[k];
            Snum += A * Bv;
            Spt  += A * s[k];
        }
        float acc = 0.f;
        #pragma unroll
        for (int k = 0; k < KK; ++k) {
            const float A = Arow[k], Bv = Brow[k];
            acc += A * Bv * __logf(Bv / s[k]);
        }
        const float kl = acc / Snum + __logf(Spt / Snum);
        if (m_on) { val = kl; cnt = 1.f; }
    }

    // ---- block reduction of (val, cnt) ----
    float v = val, c = cnt;
    #pragma unroll
    for (int off = 32; off > 0; off >>= 1) {
        v += __shfl_down(v, off);
        c += __shfl_down(c, off);
    }
    if ((tid & 63) == 0) {
        const int w = tid >> 6;
        s_red[w * 2]     = v;
        s_red[w * 2 + 1] = c;
    }
    __syncthreads();
    if (tid == 0) {
        float V = 0.f, C = 0.f;
        #pragma unroll
        for (int w = 0; w < 4; ++w) { V += s_red[w * 2]; C += s_red[w * 2 + 1]; }
        ws[(size_t)(b * NCH + ch) * 2]     = V;
        ws[(size_t)(b * NCH + ch) * 2 + 1] = C;
    }
}

__global__ __launch_bounds__(64) void lvb_final(const float* __restrict__ ws,
                                                float* __restrict__ out)
{
    const int b = threadIdx.x;   // 64 threads == 1 wave == B
    float v = 0.f, c = 0.f;
    #pragma unroll
    for (int ch = 0; ch < NCH; ++ch) {
        v += ws[(b * NCH + ch) * 2];
        c += ws[(b * NCH + ch) * 2 + 1];
    }
    float per = (c > 0.f) ? v / fmaxf(c, 1.f) : 0.f;
    #pragma unroll
    for (int off = 32; off > 0; off >>= 1) per += __shfl_down(per, off);
    if (b == 0) out[0] = per / (float)BB;
}

extern "C" void kernel_launch(void* const* d_in, const int* in_sizes, int n_in,
                              void* d_out, int out_size, void* d_ws, size_t ws_size,
                              hipStream_t stream) {
    const float* src  = (const float*)d_in[0];
    const float* q    = (const float*)d_in[1];
    const float* pred = (const float*)d_in[2];
    const int*   tgt  = (const int*)d_in[3];
    // d_in[4] = tgt_onehot — not needed (tgt ints suffice)
    const float* mask = (const float*)d_in[5];
    const int*   ts   = (const int*)d_in[6];
    const float* Qm   = (const float*)d_in[7];
    const float* Qb   = (const float*)d_in[8];
    float* ws  = (float*)d_ws;
    float* out = (float*)d_out;

    dim3 grid(NCH, BB);
    hipLaunchKernelGGL(lvb_main, grid, dim3(256), 0, stream,
                       src, q, pred, tgt, mask, ts, Qm, Qb, ws);
    hipLaunchKernelGGL(lvb_final, dim3(1), dim3(64), 0, stream, ws, out);
}

// Round 7
// 122.529 us; speedup vs baseline: 1.1352x; 1.1352x over previous
//
#include <hip/hip_runtime.h>

#define BB 64
#define LL 2048
#define KK 30
#define VV 33
#define TTMAX 500
#define CHUNK 128          // positions per block
#define NCH (LL / CHUNK)   // 16 chunks per batch
#define TS 36              // Q-table stride: 16B-aligned rows, bank-offset 4/row

__global__ __launch_bounds__(256, 4) void lvb_main(
    const float* __restrict__ src, const float* __restrict__ q,
    const float* __restrict__ pred, const int* __restrict__ tgt,
    const float* __restrict__ mask, const int* __restrict__ tsteps,
    const float* __restrict__ Qm, const float* __restrict__ Qbar,
    float* __restrict__ ws)
{
    __shared__ float s_tile[CHUNK * VV];   // pred rows (stride 33, odd => divergent-row reads conflict-free)
    __shared__ float s_qbm1[KK * TS];      // Q_bar[t-1], padded cols 30,31 = 1.0
    __shared__ float s_logQ[KK * TS];      // log(Q_bar[t-1]), padded cols = 0
    __shared__ float s_qtT [KK * TS];      // Q[t]^T: [x][k] = Qt[k][x], padded cols = 0
    __shared__ int   s_xt[CHUNK];
    __shared__ float s_red[8];

    const int tid   = threadIdx.x;
    const int lane  = tid & 63;
    const int wid   = tid >> 6;
    const int khalf = lane >> 5;           // 0: k in [0,16), 1: k in [16,32)
    const int kb    = khalf << 4;
    const int pos   = wid * 32 + (lane & 31);   // [0, 128)
    const int ch    = blockIdx.x;
    const int b     = blockIdx.y;
    const int l0    = ch * CHUNK;
    const int idx   = b * LL + l0 + pos;
    const int t     = tsteps[b];

    float val = 0.f, cnt = 0.f;
    const bool m_on = (mask[idx] > 0.5f);

    if (t == 1) {
        // ---- cross-entropy: predictions + tgt only ----
        const float* g = pred + (size_t)(b * LL + l0) * VV;
        for (int i = tid; i < CHUNK * VV; i += 256) s_tile[i] = g[i];
        __syncthreads();
        const float* row = &s_tile[pos * VV];
        float mx = row[0];
        #pragma unroll
        for (int j = 1; j < KK; ++j) mx = fmaxf(mx, row[j]);
        float se = 0.f;
        #pragma unroll
        for (int j = 0; j < KK; ++j) se += __expf(row[j] - mx);
        const int tg = tgt[idx];
        const float ce = -(row[tg] - mx - __logf(se));
        if (m_on) { val = ce; cnt = 1.f; }
    } else if (t == TTMAX) {
        // ---- KL vs uniform prior: q only ----
        const float* g = q + (size_t)(b * LL + l0) * KK;
        for (int i = tid; i < CHUNK * KK; i += 256) {
            int r = i / KK, c = i - r * KK;
            s_tile[r * VV + c] = g[i];
        }
        __syncthreads();
        const float* row = &s_tile[pos * VV];
        float S = 0.f, t1 = 0.f;
        #pragma unroll
        for (int j = 0; j < KK; ++j) { float v = row[j]; S += v; t1 += v * __logf(v); }
        const float klp = t1 / S - __logf(S) + __logf((float)KK);
        if (m_on) { val = klp; cnt = 1.f; }
    } else {
        // ---- middle KL branch, 2-way k-split per position ----
        const float* g = pred + (size_t)(b * LL + l0) * VV;
        for (int i = tid; i < CHUNK * VV; i += 256) s_tile[i] = g[i];

        const int tm1 = (t - 1 > 0) ? t - 1 : 0;
        const float* gq = Qbar + (size_t)tm1 * KK * KK;
        const float* gt = Qm + (size_t)t * KK * KK;
        // 30 rows x 32 cols (padded). i in [0, 960)
        for (int i = tid; i < KK * 32; i += 256) {
            int r = i >> 5, c = i & 31;
            float bv = (c < KK) ? gq[r * KK + c] : 1.0f;
            s_qbm1[r * TS + c] = bv;
            s_logQ[r * TS + c] = (c < KK) ? __logf(bv) : 0.f;
            s_qtT [r * TS + c] = (c < KK) ? gt[c * KK + r] : 0.f;
        }
        const float* gs = src + (size_t)(b * LL + l0) * KK;
        for (int i = tid; i < CHUNK * KK; i += 256) {
            if (gs[i] > 0.5f) { int r = i / KK; s_xt[r] = i - r * KK; }
        }
        __syncthreads();

        const float* row = &s_tile[pos * VV];
        // pass 1: max + softmax denominator
        float mx = row[0];
        #pragma unroll
        for (int j = 1; j < KK; ++j) mx = fmaxf(mx, row[j]);
        float se = 0.f;
        #pragma unroll
        for (int j = 0; j < KK; ++j) se += __expf(row[j] - mx);
        const float inv2 = 1.f / (se * se);

        // pass 2: s[c] = sum_j e_j^2 * Qbm1[j][kb+c]  (scaled by inv2 later)
        float s[16];
        #pragma unroll
        for (int c = 0; c < 16; ++c) s[c] = 0.f;
        #pragma unroll
        for (int j = 0; j < KK; ++j) {
            const float p2j = __expf(2.f * (row[j] - mx));   // e_j^2
            const float4* strip = reinterpret_cast<const float4*>(&s_qbm1[j * TS + kb]);
            #pragma unroll
            for (int c4 = 0; c4 < 4; ++c4) {
                const float4 v = strip[c4];
                s[c4 * 4 + 0] += p2j * v.x;
                s[c4 * 4 + 1] += p2j * v.y;
                s[c4 * 4 + 2] += p2j * v.z;
                s[c4 * 4 + 3] += p2j * v.w;
            }
        }

        const int tg = tgt[idx];
        const int xt = s_xt[pos];
        const float4* Af = reinterpret_cast<const float4*>(&s_qtT [xt * TS + kb]);
        const float4* Bf = reinterpret_cast<const float4*>(&s_qbm1[tg * TS + kb]);
        const float4* Lf = reinterpret_cast<const float4*>(&s_logQ[tg * TS + kb]);

        float Snum = 0.f, Spt = 0.f, acc = 0.f;
        #pragma unroll
        for (int c4 = 0; c4 < 4; ++c4) {
            const float4 Av = Af[c4], Bv = Bf[c4], Lv = Lf[c4];
            #pragma unroll
            for (int e = 0; e < 4; ++e) {
                const float A  = (&Av.x)[e];
                const float Bm = (&Bv.x)[e];
                const float Lb = (&Lv.x)[e];
                const float sk = s[c4 * 4 + e] * inv2;
                const float AB = A * Bm;
                Snum += AB;
                Spt  += A * sk;
                acc  += AB * (Lb - __logf(sk));
            }
        }
        // combine the two k-halves
        Snum += __shfl_xor(Snum, 32);
        Spt  += __shfl_xor(Spt, 32);
        acc  += __shfl_xor(acc, 32);

        const float kl = acc / Snum + __logf(Spt / Snum);
        if (m_on) { val = kl; cnt = 1.f; }
    }

    // each position is held by 2 lanes; count only khalf==0
    if (khalf) { val = 0.f; cnt = 0.f; }

    // ---- block reduction of (val, cnt) ----
    float v = val, c = cnt;
    #pragma unroll
    for (int off = 32; off > 0; off >>= 1) {
        v += __shfl_down(v, off);
        c += __shfl_down(c, off);
    }
    if (lane == 0) { s_red[wid * 2] = v; s_red[wid * 2 + 1] = c; }
    __syncthreads();
    if (tid == 0) {
        float V = 0.f, C = 0.f;
        #pragma unroll
        for (int w = 0; w < 4; ++w) { V += s_red[w * 2]; C += s_red[w * 2 + 1]; }
        ws[(size_t)(b * NCH + ch) * 2]     = V;
        ws[(size_t)(b * NCH + ch) * 2 + 1] = C;
    }
}

__global__ __launch_bounds__(64) void lvb_final(const float* __restrict__ ws,
                                                float* __restrict__ out)
{
    const int b = threadIdx.x;   // 64 threads == 1 wave == B
    float v = 0.f, c = 0.f;
    #pragma unroll
    for (int ch = 0; ch < NCH; ++ch) {
        v += ws[(b * NCH + ch) * 2];
        c += ws[(b * NCH + ch) * 2 + 1];
    }
    float per = (c > 0.f) ? v / fmaxf(c, 1.f) : 0.f;
    #pragma unroll
    for (int off = 32; off > 0; off >>= 1) per += __shfl_down(per, off);
    if (b == 0) out[0] = per / (float)BB;
}

extern "C" void kernel_launch(void* const* d_in, const int* in_sizes, int n_in,
                              void* d_out, int out_size, void* d_ws, size_t ws_size,
                              hipStream_t stream) {
    const float* src  = (const float*)d_in[0];
    const float* q    = (const float*)d_in[1];
    const float* pred = (const float*)d_in[2];
    const int*   tgt  = (const int*)d_in[3];
    // d_in[4] = tgt_onehot — not needed (tgt ints suffice)
    const float* mask = (const float*)d_in[5];
    const int*   ts   = (const int*)d_in[6];
    const float* Qm   = (const float*)d_in[7];
    const float* Qb   = (const float*)d_in[8];
    float* ws  = (float*)d_ws;
    float* out = (float*)d_out;

    dim3 grid(NCH, BB);
    hipLaunchKernelGGL(lvb_main, grid, dim3(256), 0, stream,
                       src, q, pred, tgt, mask, ts, Qm, Qb, ws);
    hipLaunchKernelGGL(lvb_final, dim3(1), dim3(64), 0, stream, ws, out);
}

// Round 9
// 114.471 us; speedup vs baseline: 1.2151x; 1.0704x over previous
//
#include <hip/hip_runtime.h>

#define BB 64
#define LL 2048
#define KK 30
#define VV 33
#define TTMAX 500
#define CHUNK 128          // positions per block
#define NCH (LL / CHUNK)   // 16 chunks per batch
#define TS 36              // Q-table stride: 16B-aligned rows, conflict-spread
#define P4 1056            // CHUNK*VV/4 pred float4s per block
#define S4 960             // CHUNK*KK/4 src/q float4s per block
#define Q4 225             // KK*KK/4 Q-table float4s

__global__ __launch_bounds__(256, 4) void lvb_main(
    const float* __restrict__ src, const float* __restrict__ q,
    const float* __restrict__ pred, const int* __restrict__ tgt,
    const float* __restrict__ mask, const int* __restrict__ tsteps,
    const float* __restrict__ Qm, const float* __restrict__ Qbar,
    float* __restrict__ ws)
{
    __shared__ __align__(16) float s_tile[CHUNK * VV]; // pred/q rows, odd stride 33
    __shared__ float s_qbm1[KK * TS];      // Q_bar[t-1], cols 30,31 = 1.0
    __shared__ float s_logQ[KK * TS];      // log(Q_bar[t-1]), pad = 0
    __shared__ float s_qtT [KK * TS];      // Q[t]^T: [x][k] = Qt[k][x], pad = 0
    __shared__ int   s_xt[CHUNK];
    __shared__ float s_red[8];

    const int tid   = threadIdx.x;
    const int lane  = tid & 63;
    const int wid   = tid >> 6;
    const int khalf = lane >> 5;           // 0: k in [0,16), 1: k in [16,32)
    const int kb    = khalf << 4;
    const int pos   = wid * 32 + (lane & 31);   // [0, 128)
    const int ch    = blockIdx.x;
    const int b     = blockIdx.y;
    const int l0    = ch * CHUNK;
    const int idx   = b * LL + l0 + pos;
    const int t     = tsteps[b];

    float val = 0.f, cnt = 0.f;
    const bool m_on = (mask[idx] > 0.5f);

    if (t == 1) {
        // ---- cross-entropy: predictions + tgt only ----
        const float4* gp4 = reinterpret_cast<const float4*>(pred + (size_t)(b * LL + l0) * VV);
        float4* st4 = reinterpret_cast<float4*>(s_tile);
        const float4 p0 = gp4[tid], p1 = gp4[tid + 256], p2 = gp4[tid + 512], p3 = gp4[tid + 768];
        float4 p4v = {0.f, 0.f, 0.f, 0.f};
        const bool hp4 = tid < (P4 - 1024);
        if (hp4) p4v = gp4[tid + 1024];
        st4[tid] = p0; st4[tid + 256] = p1; st4[tid + 512] = p2; st4[tid + 768] = p3;
        if (hp4) st4[tid + 1024] = p4v;
        __syncthreads();
        const float* row = &s_tile[pos * VV];
        float rv[KK];
        #pragma unroll
        for (int j = 0; j < KK; ++j) rv[j] = row[j];
        float mx = rv[0];
        #pragma unroll
        for (int j = 1; j < KK; ++j) mx = fmaxf(mx, rv[j]);
        float se = 0.f;
        #pragma unroll
        for (int j = 0; j < KK; ++j) se += __expf(rv[j] - mx);
        const int tg = tgt[idx];
        const float ce = -(row[tg] - mx - __logf(se));
        if (m_on) { val = ce; cnt = 1.f; }
    } else if (t == TTMAX) {
        // ---- KL vs uniform prior: q only ----
        const float4* gq4 = reinterpret_cast<const float4*>(q + (size_t)(b * LL + l0) * KK);
        const float4 a0 = gq4[tid], a1 = gq4[tid + 256], a2 = gq4[tid + 512];
        float4 a3 = {0.f, 0.f, 0.f, 0.f};
        const bool h3 = tid < (S4 - 768);
        if (h3) a3 = gq4[tid + 768];
        // scatter packed-30 -> stride-33 LDS
        {
            #define PUTQ(x, f) { const int _f=(f); const int _r=_f/30; s_tile[_r*VV + (_f-30*_r)] = (x); }
            int i0 = 4 * tid;
            PUTQ(a0.x, i0) PUTQ(a0.y, i0+1) PUTQ(a0.z, i0+2) PUTQ(a0.w, i0+3)
            i0 = 4 * (tid + 256);
            PUTQ(a1.x, i0) PUTQ(a1.y, i0+1) PUTQ(a1.z, i0+2) PUTQ(a1.w, i0+3)
            i0 = 4 * (tid + 512);
            PUTQ(a2.x, i0) PUTQ(a2.y, i0+1) PUTQ(a2.z, i0+2) PUTQ(a2.w, i0+3)
            if (h3) {
                i0 = 4 * (tid + 768);
                PUTQ(a3.x, i0) PUTQ(a3.y, i0+1) PUTQ(a3.z, i0+2) PUTQ(a3.w, i0+3)
            }
            #undef PUTQ
        }
        __syncthreads();
        const float* row = &s_tile[pos * VV];
        float S = 0.f, t1 = 0.f;
        #pragma unroll
        for (int j = 0; j < KK; ++j) { float v = row[j]; S += v; t1 += v * __logf(v); }
        const float klp = t1 / S - __logf(S) + __logf((float)KK);
        if (m_on) { val = klp; cnt = 1.f; }
    } else {
        // ---- middle KL branch, 2-way k-split per position ----
        // 1) issue ALL global loads into registers first (latency overlap)
        const float4* gp4 = reinterpret_cast<const float4*>(pred + (size_t)(b * LL + l0) * VV);
        const float4 p0 = gp4[tid], p1 = gp4[tid + 256], p2 = gp4[tid + 512], p3 = gp4[tid + 768];
        float4 p4v = {0.f, 0.f, 0.f, 0.f};
        const bool hp4 = tid < (P4 - 1024);
        if (hp4) p4v = gp4[tid + 1024];

        const float4* gs4 = reinterpret_cast<const float4*>(src + (size_t)(b * LL + l0) * KK);
        const float4 sv0 = gs4[tid], sv1 = gs4[tid + 256], sv2 = gs4[tid + 512];
        float4 sv3 = {0.f, 0.f, 0.f, 0.f};
        const bool hs3 = tid < (S4 - 768);
        if (hs3) sv3 = gs4[tid + 768];

        const int tm1 = (t - 1 > 0) ? t - 1 : 0;
        const float4* gq4 = reinterpret_cast<const float4*>(Qbar + (size_t)tm1 * KK * KK);
        const float4* gt4 = reinterpret_cast<const float4*>(Qm + (size_t)t * KK * KK);
        float4 qv = {0.f, 0.f, 0.f, 0.f}, tv = {0.f, 0.f, 0.f, 0.f};
        const bool hq = tid < Q4;
        if (hq) { qv = gq4[tid]; tv = gt4[tid]; }

        // 2) Q-tables -> LDS with logs (overlaps pred/src load latency)
        if (hq) {
            #define PUTT(xq, xt_, f) { const int _f=(f); const int _r=_f/30; const int _c=_f-30*_r; \
                s_qbm1[_r*TS+_c] = (xq); s_logQ[_r*TS+_c] = __logf(xq); s_qtT[_c*TS+_r] = (xt_); }
            const int i0 = 4 * tid;
            PUTT(qv.x, tv.x, i0) PUTT(qv.y, tv.y, i0+1) PUTT(qv.z, tv.z, i0+2) PUTT(qv.w, tv.w, i0+3)
            #undef PUTT
        } else if (tid < Q4 + KK) {
            const int r = tid - Q4;   // pad cols 30,31 for row r of all three tables
            s_qbm1[r*TS+30] = 1.f; s_qbm1[r*TS+31] = 1.f;
            s_logQ[r*TS+30] = 0.f; s_logQ[r*TS+31] = 0.f;
            s_qtT [r*TS+30] = 0.f; s_qtT [r*TS+31] = 0.f;
        }

        // 3) pred regs -> LDS (b128 writes)
        float4* st4 = reinterpret_cast<float4*>(s_tile);
        st4[tid] = p0; st4[tid + 256] = p1; st4[tid + 512] = p2; st4[tid + 768] = p3;
        if (hp4) st4[tid + 1024] = p4v;

        // 4) one-hot scan from src regs
        {
            #define SCAN1(x, f) if ((x) > 0.5f) { const int _f=(f); const int _r=_f/30; s_xt[_r] = _f-30*_r; }
            int i0 = 4 * tid;
            SCAN1(sv0.x, i0) SCAN1(sv0.y, i0+1) SCAN1(sv0.z, i0+2) SCAN1(sv0.w, i0+3)
            i0 = 4 * (tid + 256);
            SCAN1(sv1.x, i0) SCAN1(sv1.y, i0+1) SCAN1(sv1.z, i0+2) SCAN1(sv1.w, i0+3)
            i0 = 4 * (tid + 512);
            SCAN1(sv2.x, i0) SCAN1(sv2.y, i0+1) SCAN1(sv2.z, i0+2) SCAN1(sv2.w, i0+3)
            if (hs3) {
                i0 = 4 * (tid + 768);
                SCAN1(sv3.x, i0) SCAN1(sv3.y, i0+1) SCAN1(sv3.z, i0+2) SCAN1(sv3.w, i0+3)
            }
            #undef SCAN1
        }
        __syncthreads();

        // 5) softmax: single exp pass, e[] kept in registers
        const float* row = &s_tile[pos * VV];
        float rv[KK];
        #pragma unroll
        for (int j = 0; j < KK; ++j) rv[j] = row[j];
        float mx = rv[0];
        #pragma unroll
        for (int j = 1; j < KK; ++j) mx = fmaxf(mx, rv[j]);
        float e[KK]; float se = 0.f;
        #pragma unroll
        for (int j = 0; j < KK; ++j) { e[j] = __expf(rv[j] - mx); se += e[j]; }
        const float inv2 = 1.f / (se * se);

        // 6) s[c] = sum_j e_j^2 * Qbm1[j][kb+c]
        float s[16];
        #pragma unroll
        for (int c = 0; c < 16; ++c) s[c] = 0.f;
        #pragma unroll
        for (int j = 0; j < KK; ++j) {
            const float p2j = e[j] * e[j];
            const float4* strip = reinterpret_cast<const float4*>(&s_qbm1[j * TS + kb]);
            #pragma unroll
            for (int c4 = 0; c4 < 4; ++c4) {
                const float4 v = strip[c4];
                s[c4 * 4 + 0] += p2j * v.x;
                s[c4 * 4 + 1] += p2j * v.y;
                s[c4 * 4 + 2] += p2j * v.z;
                s[c4 * 4 + 3] += p2j * v.w;
            }
        }

        const int tg = tgt[idx];
        const int xt = s_xt[pos];
        const float4* Af = reinterpret_cast<const float4*>(&s_qtT [xt * TS + kb]);
        const float4* Bf = reinterpret_cast<const float4*>(&s_qbm1[tg * TS + kb]);
        const float4* Lf = reinterpret_cast<const float4*>(&s_logQ[tg * TS + kb]);

        float Snum = 0.f, Spt = 0.f, acc = 0.f;
        #pragma unroll
        for (int c4 = 0; c4 < 4; ++c4) {
            const float4 Av = Af[c4], Bv = Bf[c4], Lv = Lf[c4];
            #pragma unroll
            for (int el = 0; el < 4; ++el) {
                const float A  = (&Av.x)[el];
                const float Bm = (&Bv.x)[el];
                const float Lb = (&Lv.x)[el];
                const float sk = s[c4 * 4 + el] * inv2;
                const float AB = A * Bm;
                Snum += AB;
                Spt  += A * sk;
                acc  += AB * (Lb - __logf(sk));
            }
        }
        // combine the two k-halves
        Snum += __shfl_xor(Snum, 32);
        Spt  += __shfl_xor(Spt, 32);
        acc  += __shfl_xor(acc, 32);

        const float kl = acc / Snum + __logf(Spt / Snum);
        if (m_on) { val = kl; cnt = 1.f; }
    }

    // each position is held by 2 lanes; count only khalf==0
    if (khalf) { val = 0.f; cnt = 0.f; }

    // ---- block reduction of (val, cnt) ----
    float v = val, c = cnt;
    #pragma unroll
    for (int off = 32; off > 0; off >>= 1) {
        v += __shfl_down(v, off);
        c += __shfl_down(c, off);
    }
    if (lane == 0) { s_red[wid * 2] = v; s_red[wid * 2 + 1] = c; }
    __syncthreads();
    if (tid == 0) {
        float V = 0.f, C = 0.f;
        #pragma unroll
        for (int w = 0; w < 4; ++w) { V += s_red[w * 2]; C += s_red[w * 2 + 1]; }
        ws[(size_t)(b * NCH + ch) * 2]     = V;
        ws[(size_t)(b * NCH + ch) * 2 + 1] = C;
    }
}

__global__ __launch_bounds__(64) void lvb_final(const float* __restrict__ ws,
                                                float* __restrict__ out)
{
    const int b = threadIdx.x;   // 64 threads == 1 wave == B
    float v = 0.f, c = 0.f;
    #pragma unroll
    for (int ch = 0; ch < NCH; ++ch) {
        v += ws[(b * NCH + ch) * 2];
        c += ws[(b * NCH + ch) * 2 + 1];
    }
    float per = (c > 0.f) ? v / fmaxf(c, 1.f) : 0.f;
    #pragma unroll
    for (int off = 32; off > 0; off >>= 1) per += __shfl_down(per, off);
    if (b == 0) out[0] = per / (float)BB;
}

extern "C" void kernel_launch(void* const* d_in, const int* in_sizes, int n_in,
                              void* d_out, int out_size, void* d_ws, size_t ws_size,
                              hipStream_t stream) {
    const float* src  = (const float*)d_in[0];
    const float* q    = (const float*)d_in[1];
    const float* pred = (const float*)d_in[2];
    const int*   tgt  = (const int*)d_in[3];
    // d_in[4] = tgt_onehot — not needed (tgt ints suffice)
    const float* mask = (const float*)d_in[5];
    const int*   ts   = (const int*)d_in[6];
    const float* Qm   = (const float*)d_in[7];
    const float* Qb   = (const float*)d_in[8];
    float* ws  = (float*)d_ws;
    float* out = (float*)d_out;

    dim3 grid(NCH, BB);
    hipLaunchKernelGGL(lvb_main, grid, dim3(256), 0, stream,
                       src, q, pred, tgt, mask, ts, Qm, Qb, ws);
    hipLaunchKernelGGL(lvb_final, dim3(1), dim3(64), 0, stream, ws, out);
}